// Round 7
// baseline (337.557 us; speedup 1.0000x reference)
//
#include <hip/hip_runtime.h>
#include <hip/hip_bf16.h>
#include <math.h>

typedef __attribute__((ext_vector_type(8))) short bf16x8;
typedef __attribute__((ext_vector_type(4))) float f32x4;
typedef __attribute__((ext_vector_type(16))) float f32x16;
typedef __attribute__((ext_vector_type(4))) short short4v;
typedef __attribute__((ext_vector_type(4))) int int4v;
typedef __attribute__((ext_vector_type(4))) unsigned uint4v;

__device__ __forceinline__ short f2bf(float f) {
  union { float f; unsigned u; } v; v.f = f;
  unsigned r = v.u + 0x7fffu + ((v.u >> 16) & 1u);
  return (short)(r >> 16);
}

__device__ __forceinline__ unsigned cvt_pk_bf16(float lo, float hi) {
  unsigned r;
  asm volatile("v_cvt_pk_bf16_f32 %0, %1, %2" : "=v"(r) : "v"(lo), "v"(hi));
  return r;
}

// ---------------- conversion kernels ----------------

__global__ void convert_x_kernel(const float* __restrict__ x, short* __restrict__ xb, int n) {
  int i = (blockIdx.x * blockDim.x + threadIdx.x) * 4;
  int stride = gridDim.x * blockDim.x * 4;
  for (; i < n; i += stride) {
    float4 v = *(const float4*)(x + i);
    short4v o;
    o.x = f2bf(v.x); o.y = f2bf(v.y); o.z = f2bf(v.z); o.w = f2bf(v.w);
    *(short4v*)(xb + i) = o;
  }
}

// W [2048][6144] f32 -> Wt [6144][2048] bf16
__global__ void transpose_w_kernel(const float* __restrict__ W, short* __restrict__ Wt) {
  __shared__ short tile[32][33];
  int n0 = blockIdx.x * 32, k0 = blockIdx.y * 32;
  int tx = threadIdx.x, ty = threadIdx.y; // (32, 8)
#pragma unroll
  for (int u = 0; u < 4; ++u) {
    int k = k0 + ty + u * 8;
    tile[ty + u * 8][tx] = f2bf(W[(size_t)k * 6144 + n0 + tx]);
  }
  __syncthreads();
#pragma unroll
  for (int u = 0; u < 4; ++u) {
    int n = n0 + ty + u * 8;
    Wt[(size_t)n * 2048 + k0 + tx] = tile[tx][ty + u * 8];
  }
}

// Normalize mask to u8 0/1, detecting storage layout (bool-bytes / int32 / f32).
__global__ void mask_norm_kernel(const unsigned* __restrict__ m, unsigned char* __restrict__ out, int n) {
  __shared__ int flagA, flagB;
  if (threadIdx.x == 0) { flagA = 0; flagB = 0; }
  __syncthreads();
  int a = 0, b = 0;
  for (int i = threadIdx.x; i < n / 4; i += blockDim.x) {
    unsigned wv = m[i];
    if (wv > 1u) a = 1;
    if (wv != 0u && wv != 0x3f800000u) b = 1;
  }
  if (a) atomicOr(&flagA, 1);
  if (b) atomicOr(&flagB, 1);
  __syncthreads();
  int A = flagA, B = flagB;
  for (int i = threadIdx.x; i < n; i += blockDim.x) {
    unsigned char r;
    if (!A) r = (m[i] != 0u) ? 1 : 0;
    else if (!B) r = (((const float*)m)[i] != 0.f) ? 1 : 0;
    else r = (((const unsigned char*)m)[i] != 0) ? 1 : 0;
    out[i] = r;
  }
}

// ---------------- QKV GEMM: 256^2, 8-slot half-tile ring, 2-bar phases ----------
// Ring: half h (A0,B0,B1,A1 of tile t = 4t+0..3) lives in slot h&7 (16KB each).
// Stage lead = 6 halves; vmcnt(6) per phase end; reads+stage before mid-barrier.

__global__ __launch_bounds__(512, 2) void qkv_gemm_kernel(
    const short* __restrict__ A, const short* __restrict__ Bt, const float* __restrict__ bias,
    short* __restrict__ qws, short* __restrict__ kws, short* __restrict__ vtws) {
  __shared__ __align__(16) char smem[131072];

  int lid = blockIdx.x;                 // 384 blocks
  int swz = (lid & 7) * 48 + (lid >> 3);
  int tm = swz / 24, tn = swz % 24;
  int m0 = tm * 256, n0 = tn * 256;
  int t = threadIdx.x, lane = t & 63, w = t >> 6;
  int wr = w >> 2, wc = w & 3;
  int g = lane >> 4, c = lane & 15;

#define SLOT(s) (smem + (s) * 16384)

#define STAGE(s, gbase)                                                                    \
  { _Pragma("unroll")                                                                      \
    for (int rr = 0; rr < 2; ++rr) {                                                       \
      int ci = rr * 512 + t;                                                               \
      int row_ = ci >> 3, ch_ = ci & 7;                                                    \
      const short* gp_ = (gbase) + (size_t)row_ * 2048 + ((ch_ ^ (row_ & 7)) * 8);         \
      __builtin_amdgcn_global_load_lds((const __attribute__((address_space(1))) void*)gp_, \
          (__attribute__((address_space(3))) void*)(SLOT(s) + ci * 16), 16, 0, 0);         \
    } }

#define LD_A(s)                                                                             \
  { const char* ab_ = SLOT(s);                                                              \
    _Pragma("unroll")                                                                       \
    for (int mi = 0; mi < 4; ++mi) {                                                        \
      int row_ = wr * 16 + c + mi * 32;                                                     \
      _Pragma("unroll")                                                                     \
      for (int ks = 0; ks < 2; ++ks)                                                        \
        af[mi][ks] = *(const bf16x8*)(ab_ + row_ * 128 + (((ks * 4 + g) ^ (row_ & 7)) * 16)); \
    } }
#define LD_B(s, R)                                                                          \
  { const char* bb_ = SLOT(s);                                                              \
    _Pragma("unroll")                                                                       \
    for (int nj = 0; nj < 2; ++nj) {                                                        \
      int row_ = wc * 16 + c + nj * 64;                                                     \
      _Pragma("unroll")                                                                     \
      for (int ks = 0; ks < 2; ++ks)                                                        \
        R[nj][ks] = *(const bf16x8*)(bb_ + row_ * 128 + (((ks * 4 + g) ^ (row_ & 7)) * 16)); \
    } }
#define MFMA16(MI0, NJ0, BF)                                                                \
  __builtin_amdgcn_s_setprio(1);                                                            \
  _Pragma("unroll")                                                                         \
  for (int mi = 0; mi < 4; ++mi)                                                            \
    _Pragma("unroll")                                                                       \
    for (int nj = 0; nj < 2; ++nj)                                                          \
      _Pragma("unroll")                                                                     \
      for (int ks = 0; ks < 2; ++ks)                                                        \
        acc[(MI0) + mi][(NJ0) + nj] =                                                       \
            __builtin_amdgcn_mfma_f32_16x16x32_bf16(af[mi][ks], BF[nj][ks],                 \
                                                    acc[(MI0) + mi][(NJ0) + nj], 0, 0, 0);  \
  __builtin_amdgcn_s_setprio(0);

#define BAR() __builtin_amdgcn_s_barrier()
#define VMC(N) asm volatile("s_waitcnt vmcnt(" #N ")" ::: "memory")

  const short* Ab0 = A + (size_t)m0 * 2048;
  const short* Ab1 = A + (size_t)(m0 + 128) * 2048;
  const short* Bb0 = Bt + (size_t)n0 * 2048;
  const short* Bb1 = Bt + (size_t)(n0 + 128) * 2048;

  f32x4 acc[8][4] = {};
  bf16x8 af[4][2], b0r[2][2], b1r[2][2];

  // prologue: halves 0..5 (tile0 complete + A0,B0 of tile1)
  STAGE(0, Ab0); STAGE(1, Bb0); STAGE(2, Bb1); STAGE(3, Ab1);
  STAGE(4, Ab0 + 64); STAGE(5, Bb0 + 64);
  VMC(8);   // halves 0,1 landed
  BAR();

  for (int tk = 0; tk < 30; ++tk) {
    int P2 = (tk & 1) * 4, Q2 = P2 ^ 4;
    int kb = tk * 64;
    // ph1: quadrant (0,0)
    LD_A(P2 + 0); LD_B(P2 + 1, b0r);
    STAGE(Q2 + 2, Bb1 + kb + 64);       // B1(t+1)
    BAR();
    MFMA16(0, 0, b0r);
    VMC(6); BAR();
    // ph2: (0,2) reuse af
    LD_B(P2 + 2, b1r);
    STAGE(Q2 + 3, Ab1 + kb + 64);       // A1(t+1)
    BAR();
    MFMA16(0, 2, b1r);
    VMC(6); BAR();
    // ph3: (4,2) reuse b1r
    LD_A(P2 + 3);
    STAGE(P2 + 0, Ab0 + kb + 128);      // A0(t+2)
    BAR();
    MFMA16(4, 2, b1r);
    VMC(6); BAR();
    // ph4: (4,0) reuse af + b0r
    STAGE(P2 + 1, Bb0 + kb + 128);      // B0(t+2)
    BAR();
    MFMA16(4, 0, b0r);
    VMC(6); BAR();
  }

  // ---- tk = 30 (P2=0, Q2=4, kb=1920): stages only at ph1/ph2 ----
  {
    LD_A(0); LD_B(1, b0r);
    STAGE(6, Bb1 + 1984);               // B1(31)
    BAR(); MFMA16(0, 0, b0r); VMC(6); BAR();
    LD_B(2, b1r);
    STAGE(7, Ab1 + 1984);               // A1(31)
    BAR(); MFMA16(0, 2, b1r); VMC(6); BAR();
    LD_A(3);
    BAR(); MFMA16(4, 2, b1r); VMC(6); BAR();
    BAR(); MFMA16(4, 0, b0r); VMC(4); BAR();
  }
  // ---- tk = 31 (P2=4): no stages; drain ----
  {
    LD_A(4); LD_B(5, b0r);
    BAR(); MFMA16(0, 0, b0r); VMC(2); BAR();
    LD_B(6, b1r);
    BAR(); MFMA16(0, 2, b1r); VMC(0); BAR();
    LD_A(7);
    BAR(); MFMA16(4, 2, b1r); BAR();
    BAR(); MFMA16(4, 0, b0r); BAR();
  }

  // ---------------- epilogue (unchanged) ----------------
  int sec = n0 >> 11;
  int b = m0 >> 11;
  int s0 = m0 & 2047;
  int nsec = n0 & 2047;

  if (sec < 2) {
    short* base = (sec == 0 ? qws : kws);
    const float scq = (sec == 0) ? (0.08838834764831845f * 1.4426950408889634f) : 1.0f;
#pragma unroll
    for (int nj = 0; nj < 4; ++nj) {
      int colsec = nsec + wc * 16 + nj * 64;
      float bv = bias[n0 + wc * 16 + nj * 64 + c];
      int h = colsec >> 7;
      int d = (colsec & 127) + c;
      short* dst = base + ((size_t)(b * 16 + h)) * (2048 * 128) + d;
#pragma unroll
      for (int mi = 0; mi < 8; ++mi) {
        int srow = s0 + (wr + 2 * mi) * 16 + g * 4;
#pragma unroll
        for (int r = 0; r < 4; ++r)
          dst[(size_t)(srow + r) * 128] = f2bf((acc[mi][nj][r] + bv) * scq);
      }
    }
  } else {
    __builtin_amdgcn_s_barrier();
    char* wreg = smem + w * 16384;
#pragma unroll
    for (int nj = 0; nj < 4; ++nj) {
      float bv = bias[n0 + wc * 16 + nj * 64 + c];
      int d = nj * 16 + c;
#pragma unroll
      for (int mi = 0; mi < 8; ++mi)
#pragma unroll
        for (int r = 0; r < 4; ++r) {
          int sloc = mi * 16 + g * 4 + r;
          *(short*)(wreg + d * 256 + (((sloc >> 3) ^ (d & 15)) * 16) + (sloc & 7) * 2) =
              f2bf(acc[mi][nj][r] + bv);
        }
    }
#pragma unroll
    for (int q = 0; q < 16; ++q) {
      int d = q * 4 + g;
      bf16x8 v = *(const bf16x8*)(wreg + d * 256 + ((c ^ (d & 15)) * 16));
      int colsec = nsec + wc * 16 + (d >> 4) * 64 + (d & 15);
      int h = colsec >> 7, dloc = colsec & 127;
      int srow = s0 + wr * 16 + (c >> 1) * 32 + (c & 1) * 8;
      *(bf16x8*)(vtws + ((size_t)(b * 16 + h)) * (128 * 2048) + (size_t)dloc * 2048 + srow) = v;
    }
  }
#undef SLOT
#undef STAGE
#undef LD_A
#undef LD_B
#undef MFMA16
#undef BAR
#undef VMC
}

// ---------------- flash attention (swapped 32x32x16, reg-P, 1-tile pipeline) ----

__global__ __launch_bounds__(256, 2) void attn_kernel(
    const short* __restrict__ qws, const short* __restrict__ kws, const short* __restrict__ vtws,
    const unsigned char* __restrict__ maskb, float* __restrict__ out) {
  __shared__ short Ks[2][32 * 128];   // [kv 32][d 128], chunk ^= (row&7)
  __shared__ short Vs[2][128 * 32];   // [d 128][kv 32], chunk ^= ((row>>1)&3)
  __shared__ float biasLds[2048];
  __shared__ int flagsLds[64];

  const int S = 2048, HD = 128;
  int lid = blockIdx.x;                    // 512 blocks
  int swz = (lid & 7) * 64 + (lid >> 3);
  int bh = swz >> 4, qblk = swz & 15;
  int b = bh >> 4, h = bh & 15;
  int t = threadIdx.x, lane = t & 63, w = t >> 6;
  int ql = lane & 31, hi = lane >> 5;
  int q0 = qblk * 128 + w * 32;
  const short* Q = qws + (size_t)bh * S * HD;
  const short* Kp = kws + (size_t)bh * S * HD;
  const short* Vt = vtws + (size_t)bh * HD * S;
  const unsigned char* mk = maskb + b * S;
  const float NEG = -3.4028235e38f;

#define STAGE_KV(buf, kv0_)                                                              \
  {                                                                                      \
    _Pragma("unroll")                                                                    \
    for (int rr = 0; rr < 2; ++rr) {                                                     \
      int ci = rr * 256 + t;                                                             \
      int r = ci >> 4, cin = ci & 15;                                                    \
      const short* gk = Kp + (size_t)((kv0_) + r) * HD + ((cin ^ (r & 7)) * 8);          \
      __builtin_amdgcn_global_load_lds((const __attribute__((address_space(1))) void*)gk,\
          (__attribute__((address_space(3))) void*)(&Ks[buf][0] + ci * 8), 16, 0, 0);    \
    }                                                                                    \
    _Pragma("unroll")                                                                    \
    for (int rr = 0; rr < 2; ++rr) {                                                     \
      int ci = rr * 256 + t;                                                             \
      int r = ci >> 2, cin = ci & 3;                                                     \
      const short* gv = Vt + (size_t)r * S + (kv0_) + ((cin ^ ((r >> 1) & 3)) * 8);      \
      __builtin_amdgcn_global_load_lds((const __attribute__((address_space(1))) void*)gv,\
          (__attribute__((address_space(3))) void*)(&Vs[buf][0] + ci * 8), 16, 0, 0);    \
    }                                                                                    \
  }

#define QK_PHASE(CUR)                                                                    \
  { const short* ks = &Ks[CUR][0];                                                       \
    _Pragma("unroll") for (int r = 0; r < 16; ++r) sv[r] = 0.f;                          \
    __builtin_amdgcn_s_setprio(1);                                                       \
    _Pragma("unroll") for (int kc = 0; kc < 8; ++kc) {                                   \
      int chunk = (kc * 2 + hi) ^ (ql & 7);                                              \
      bf16x8 kf = *(const bf16x8*)(ks + ql * 128 + chunk * 8);                           \
      sv = __builtin_amdgcn_mfma_f32_32x32x16_bf16(kf, qf[kc], sv, 0, 0, 0);             \
    }                                                                                    \
    __builtin_amdgcn_s_setprio(0); }

#define PV_PHASE()                                                                       \
  { __builtin_amdgcn_s_setprio(1);                                                       \
    _Pragma("unroll") for (int dt = 0; dt < 4; ++dt)                                     \
      _Pragma("unroll") for (int kt = 0; kt < 2; ++kt)                                   \
        acc[dt] = __builtin_amdgcn_mfma_f32_32x32x16_bf16(vreg[dt * 2 + kt], pfv[kt],    \
                                                          acc[dt], 0, 0, 0);             \
    __builtin_amdgcn_s_setprio(0); }

#define LOADV(CUR)                                                                       \
  { const short* vs = &Vs[CUR][0];                                                       \
    _Pragma("unroll") for (int dt = 0; dt < 4; ++dt)                                     \
      _Pragma("unroll") for (int kt = 0; kt < 2; ++kt) {                                 \
        int d = dt * 32 + ql;                                                            \
        int chunk = (kt * 2 + hi) ^ ((d >> 1) & 3);                                      \
        vreg[dt * 2 + kt] = *(const bf16x8*)(vs + d * 32 + chunk * 8);                   \
      } }

#define SOFTMAX_PACK(IT_)                                                                \
  { int kv0s = (IT_) * 32;                                                               \
    float p[16];                                                                         \
    if ((fmask >> (IT_)) & 1ull) {                                                       \
      _Pragma("unroll") for (int r = 0; r < 16; ++r) p[r] = sv[r];                       \
    } else {                                                                             \
      _Pragma("unroll") for (int g2 = 0; g2 < 4; ++g2) {                                 \
        f32x4 bb = *(const f32x4*)(biasLds + kv0s + g2 * 8 + hi * 4);                    \
        _Pragma("unroll") for (int j = 0; j < 4; ++j)                                    \
          p[g2 * 4 + j] = sv[g2 * 4 + j] + bb[j];                                        \
      }                                                                                  \
    }                                                                                    \
    float a0 = fmaxf(fmaxf(p[0], p[1]), fmaxf(p[2], p[3]));                              \
    float a1 = fmaxf(fmaxf(p[4], p[5]), fmaxf(p[6], p[7]));                              \
    float a2 = fmaxf(fmaxf(p[8], p[9]), fmaxf(p[10], p[11]));                            \
    float a3 = fmaxf(fmaxf(p[12], p[13]), fmaxf(p[14], p[15]));                          \
    float rmx = fmaxf(fmaxf(a0, a1), fmaxf(a2, a3));                                     \
    rmx = fmaxf(rmx, __shfl_xor(rmx, 32));                                               \
    if (__any(rmx > m_ + 12.f)) {                                                        \
      float mn = fmaxf(m_, rmx);                                                         \
      float al = exp2f(m_ - mn);                                                         \
      m_ = mn; lp *= al;                                                                 \
      _Pragma("unroll") for (int dt = 0; dt < 4; ++dt)                                   \
        _Pragma("unroll") for (int r = 0; r < 16; ++r) acc[dt][r] *= al;                 \
    }                                                                                    \
    _Pragma("unroll") for (int r = 0; r < 16; ++r) p[r] = exp2f(p[r] - m_);              \
    lp += (((p[0] + p[1]) + (p[2] + p[3])) + ((p[4] + p[5]) + (p[6] + p[7])))            \
        + (((p[8] + p[9]) + (p[10] + p[11])) + ((p[12] + p[13]) + (p[14] + p[15])));     \
    _Pragma("unroll") for (int kt = 0; kt < 2; ++kt) {                                   \
      unsigned Aw = cvt_pk_bf16(p[kt * 8 + 0], p[kt * 8 + 1]);                           \
      unsigned Bw = cvt_pk_bf16(p[kt * 8 + 2], p[kt * 8 + 3]);                           \
      unsigned Cw = cvt_pk_bf16(p[kt * 8 + 4], p[kt * 8 + 5]);                           \
      unsigned Dw = cvt_pk_bf16(p[kt * 8 + 6], p[kt * 8 + 7]);                           \
      asm volatile("v_permlane32_swap_b32 %0, %1" : "+v"(Aw), "+v"(Cw));                 \
      asm volatile("v_permlane32_swap_b32 %0, %1" : "+v"(Bw), "+v"(Dw));                 \
      uint4v uu; uu.x = Aw; uu.y = Bw; uu.z = Cw; uu.w = Dw;                             \
      pfv[kt] = __builtin_bit_cast(bf16x8, uu);                                          \
    } }

  // Q fragments: B-operand, lane: col=q=ql, k-slice (d) = kc*16 + hi*8
  bf16x8 qf[8];
#pragma unroll
  for (int kc = 0; kc < 8; ++kc)
    qf[kc] = *(const bf16x8*)(Q + (size_t)(q0 + ql) * HD + kc * 16 + hi * 8);

  for (int i = t; i < 2048; i += 256) biasLds[i] = mk[i] ? 0.f : NEG;
  STAGE_KV(0, 0);
  __syncthreads();
  if (t < 64) {
    int ok = 1;
    for (int j = 0; j < 32; ++j) ok &= (biasLds[t * 32 + j] == 0.f) ? 1 : 0;
    flagsLds[t] = ok;
  }
  __syncthreads();
  unsigned long long fmask = __ballot(flagsLds[lane] != 0);

  f32x16 acc[4] = {};
  float m_ = NEG, lp = 0.f;
  f32x16 sv;
  bf16x8 pfv[2];
  bf16x8 vreg[8];

  // ---- iter 0 (peeled: no PV yet) ----
  QK_PHASE(0);
  STAGE_KV(1, 32);
  SOFTMAX_PACK(0);
  LOADV(0);
  __syncthreads();

  for (int it = 1; it < 64; ++it) {
    int cur = it & 1;
    QK_PHASE(cur);
    if (it < 63) STAGE_KV(cur ^ 1, it * 32 + 32);
    PV_PHASE();        // tile it-1, from registers (vreg/pfv)
    LOADV(cur);        // V(it) -> regs for next iter's PV
    SOFTMAX_PACK(it);  // overlaps MFMA tail; rewrites pfv for next PV
    __syncthreads();   // drains prefetch vmcnt + buffer swap
  }
  PV_PHASE();          // tail: tile 63

  // final l: combine the two k-halves, then normalize + write
  lp += __shfl_xor(lp, 32);
  float inv = 1.f / lp;
  size_t orow = (size_t)(b * 2048 + q0 + ql) * 2048 + h * 128;
#pragma unroll
  for (int dt = 0; dt < 4; ++dt)
#pragma unroll
    for (int g2 = 0; g2 < 4; ++g2) {
      f32x4 v;
      v[0] = acc[dt][g2 * 4 + 0] * inv;
      v[1] = acc[dt][g2 * 4 + 1] * inv;
      v[2] = acc[dt][g2 * 4 + 2] * inv;
      v[3] = acc[dt][g2 * 4 + 3] * inv;
      int d = dt * 32 + g2 * 8 + hi * 4;
      *(f32x4*)(out + orow + d) = v;
    }
#undef STAGE_KV
#undef QK_PHASE
#undef PV_PHASE
#undef LOADV
#undef SOFTMAX_PACK
}

// ---------------- launch ----------------

extern "C" void kernel_launch(void* const* d_in, const int* in_sizes, int n_in,
                              void* d_out, int out_size, void* d_ws, size_t ws_size,
                              hipStream_t stream) {
  const float* x = (const float*)d_in[0];
  const float* W = (const float*)d_in[1];
  const float* bias = (const float*)d_in[2];
  const void* mask = d_in[3];
  float* out = (float*)d_out;

  char* ws = (char*)d_ws;
  short* xb = (short*)(ws);
  short* wt = (short*)(ws + 16777216);
  short* qws = (short*)(ws + 41943040);
  short* kws = (short*)(ws + 58720256);
  short* vtws = (short*)(ws + 75497472);
  unsigned char* maskb = (unsigned char*)(ws + 92274688);

  convert_x_kernel<<<dim3(2048), dim3(256), 0, stream>>>(x, xb, 2 * 2048 * 2048);
  transpose_w_kernel<<<dim3(192, 64), dim3(32, 8), 0, stream>>>(W, wt);
  mask_norm_kernel<<<dim3(1), dim3(256), 0, stream>>>((const unsigned*)mask, maskb, 2 * 2048);
  qkv_gemm_kernel<<<dim3(384), dim3(512), 0, stream>>>(xb, wt, bias, qws, kws, vtws);
  attn_kernel<<<dim3(512), dim3(256), 0, stream>>>(qws, kws, vtws, maskb, out);
}